// Round 19
// baseline (858.637 us; speedup 1.0000x reference)
//
#include <hip/hip_runtime.h>
#include <math.h>

#define Bn 2
#define Cn 192
#define Dn 48
#define Hn 48
#define Wn 48
#define C4 768
#define DHW (Dn*Hn*Wn)          // 110592 per batch
#define CDHW ((long)Cn*DHW)     // 21233664 per batch

typedef __attribute__((ext_vector_type(8))) short bf16x8;
typedef __attribute__((ext_vector_type(4))) float f32x4;

__device__ inline float bf2f(unsigned short u) {
    union { float f; unsigned int i; } v; v.i = ((unsigned int)u) << 16; return v.f;
}
__device__ inline unsigned short f2bf(float f) {
    union { float f; unsigned int i; } v; v.f = f;
    unsigned int r = v.i + 0x7FFFu + ((v.i >> 16) & 1u);   // RNE
    return (unsigned short)(r >> 16);
}
__device__ inline float blo(unsigned int u) {
    union { unsigned int i; float f; } v; v.i = u << 16; return v.f;
}
__device__ inline float bhi(unsigned int u) {
    union { unsigned int i; float f; } v; v.i = u & 0xffff0000u; return v.f;
}
__device__ inline unsigned int cvtpk_bf16(float lo, float hi) {
    unsigned int r;
    asm("v_cvt_pk_bf16_f32 %0, %1, %2" : "=v"(r) : "v"(lo), "v"(hi));
    return r;
}
// tanh-form GELU: branch-free; |gelu_tanh - gelu_exact| <= ~3e-4 (r14: absmax ok)
__device__ inline float gelu_tanh(float v) {
    float u = v * fmaf(0.0356774081f, v * v, 0.7978845608f);
    float a = fabsf(u);
    float t = __expf(-2.0f * a);
    float th = (1.0f - t) / (1.0f + t);
    th = copysignf(th, u);
    return 0.5f * v * (1.0f + th);
}

// ---- x pre-pad: NCDHW f32 -> xbf[c][d][h][64] bf16, w zero-padded +-8 ----
__global__ __launch_bounds__(256)
void xpad_k(const float* __restrict__ x, unsigned short* __restrict__ xbf)
{
    int u = blockIdx.x * 256 + threadIdx.x;     // row*8 + j
    int j = u & 7;
    int row = u >> 3;                            // c*2304 + d*48 + h
    unsigned short* orow = xbf + ((size_t)row << 6);
    uint4 o = {0u, 0u, 0u, 0u};
    if (j >= 1 && j <= 6) {
        const float* xr = x + (size_t)row * 48 + (8 * j - 8);
        float4 a = *(const float4*)xr;
        float4 b = *(const float4*)(xr + 4);
        o.x = cvtpk_bf16(a.x, a.y); o.y = cvtpk_bf16(a.z, a.w);
        o.z = cvtpk_bf16(b.x, b.y); o.w = cvtpk_bf16(b.z, b.w);
    }
    *(uint4*)(orow + 8 * j) = o;
}

// ---- B-Toeplitz table: btp[(c*49+kdkh)*64+lane][j] = wt[kdkh][8g+j-n-5] ----
__global__ __launch_bounds__(256)
void btoep_k(const float* __restrict__ cw, unsigned short* __restrict__ btp)
{
    int idx = blockIdx.x * 256 + threadIdx.x;   // (c*49 + kdkh)*64 + lane
    int lane = idx & 63;
    int t = idx >> 6;
    int kdkh = t % 49, c = t / 49;
    int n = lane & 15, g = lane >> 4;
    unsigned short v[8];
#pragma unroll
    for (int j = 0; j < 8; ++j) {
        int kw = 8 * g + j - n - 5;
        v[j] = (kw >= 0 && kw <= 6) ? f2bf(cw[(kdkh * 7 + kw) * Cn + c])
                                    : (unsigned short)0;
    }
    *(uint4*)(btp + (size_t)idx * 8) = *(uint4*)v;
}

// ---------------- depthwise conv 7x7x7 on the MATRIX pipe (Toeplitz MFMA) ----
#define CTD 16
#define CHD (CTD+6)   // 22
#define CHH 22

__global__ __launch_bounds__(128)
void conv_dw(const unsigned short* __restrict__ xbf, const unsigned short* __restrict__ btp,
             const float* __restrict__ cb, unsigned short* __restrict__ yc)
{
    __shared__ unsigned int xt[CHD * CHH * 16];   // 30,976 B
    int c = blockIdx.y;
    int s = blockIdx.x;                           // 27 tiles: 3x3x3 of 16^3
    int wt = s % 3, ht = (s / 3) % 3, dt = s / 9;
    int d0 = dt * 16, h0 = ht * 16, w0 = wt * 16;
    int tid = threadIdx.x;

    const unsigned short* xc = xbf + ((size_t)c * 2304 << 6);
    for (int u = tid; u < CHD * CHH * 4; u += 128) {
        int g = u & 3, r2 = u >> 2;
        int hh2 = r2 % CHH, dd = r2 / CHH;
        int gd = d0 - 3 + dd, gh = h0 - 3 + hh2;
        uint4 v = {0u, 0u, 0u, 0u};
        if ((unsigned)gd < 48u && (unsigned)gh < 48u)
            v = *(const uint4*)(xc + (((size_t)gd * 48 + gh) << 6) + w0 + 8 * g);
        *(uint4*)&xt[(r2 << 4) + ((g ^ (r2 & 3)) << 2)] = v;
    }
    __syncthreads();

    int lane = tid & 63, wv = tid >> 6;
    int lr = lane & 15, g = lane >> 4;
    float bias = cb[c];
    f32x4 acc[8];
#pragma unroll
    for (int t = 0; t < 8; ++t) acc[t] = (f32x4){bias, bias, bias, bias};

    const unsigned short* bchan = btp + (size_t)c * 49 * 512;
    const unsigned short* xt16 = (const unsigned short*)xt;

    for (int kh = 0; kh < 7; ++kh) {
        bf16x8 Bf[7];
#pragma unroll
        for (int kd = 0; kd < 7; ++kd)
            Bf[kd] = *(const bf16x8*)(bchan + (size_t)((kd * 7 + kh) * 64 + lane) * 8);
#pragma unroll
        for (int p = 0; p < 14; ++p) {
            int r2 = (8 * wv + p) * CHH + kh + lr;
            bf16x8 Af = *(const bf16x8*)(xt16 + (r2 << 5) + ((g ^ (r2 & 3)) << 3));
#pragma unroll
            for (int kd = 0; kd < 7; ++kd) {
                int t = p - kd;
                if (t < 0 || t > 7) continue;     // folds at compile time
                acc[t] = __builtin_amdgcn_mfma_f32_16x16x32_bf16(Af, Bf[kd], acc[t], 0, 0, 0);
            }
        }
    }

    unsigned short* yb = yc + (long)c * DHW;
#pragma unroll
    for (int t = 0; t < 8; ++t) {
        int d = d0 + 8 * wv + t;
#pragma unroll
        for (int i = 0; i < 4; ++i) {
            int h = h0 + g * 4 + i;
            yb[((long)d * 48 + h) * 48 + w0 + lr] = f2bf(acc[t][i]);
        }
    }
}

// ---------------- LayerNorm over C, per-batch NCDHW(bf16) -> NDHWC (bf16) ----------------
__global__ __launch_bounds__(256)
void ln_kernel(const unsigned short* __restrict__ yc, const float* __restrict__ g,
               const float* __restrict__ lb, unsigned short* __restrict__ y1)
{
    __shared__ float tile[Cn * Wn];
    __shared__ float qs1[4][48], qs2[4][48];
    __shared__ float mu_s[Wn], rs_s[Wn];
    int dh = blockIdx.x;
    long rowbase = (long)dh * Wn;
    for (int l = threadIdx.x; l < Cn * 24; l += 256) {
        int c = l / 24, wp = l % 24;
        unsigned int u = *(const unsigned int*)&yc[rowbase + (long)c * DHW + wp * 2];
        tile[c * Wn + wp * 2]     = blo(u);
        tile[c * Wn + wp * 2 + 1] = bhi(u);
    }
    __syncthreads();
    if (threadIdx.x < 192) {
        int w = threadIdx.x >> 2, q = threadIdx.x & 3;
        float s1 = 0.f, s2 = 0.f;
        for (int cc = 0; cc < 48; ++cc) {
            float v = tile[(cc * 4 + q) * Wn + w];
            s1 += v; s2 = fmaf(v, v, s2);
        }
        qs1[q][w] = s1; qs2[q][w] = s2;
    }
    __syncthreads();
    if (threadIdx.x < 48) {
        int w = threadIdx.x;
        float s1 = qs1[0][w] + qs1[1][w] + qs1[2][w] + qs1[3][w];
        float s2 = qs2[0][w] + qs2[1][w] + qs2[2][w] + qs2[3][w];
        float mu = s1 * (1.0f / Cn);
        float var = s2 * (1.0f / Cn) - mu * mu;
        mu_s[w] = mu;
        rs_s[w] = rsqrtf(var + 1e-6f);
    }
    __syncthreads();
    long obase = (long)dh * Wn * Cn;
    for (int l = threadIdx.x; l < Cn * Wn; l += 256) {
        int w = l / Cn, c = l % Cn;
        float val = (tile[c * Wn + w] - mu_s[w]) * rs_s[w] * g[c] + lb[c];
        y1[obase + l] = f2bf(val);
    }
}

// ---------------- weight transpose+bf16: Wt[n][k] = bf16(W[k][n]) ----------------
__global__ __launch_bounds__(256)
void wtrans(const float* __restrict__ W, unsigned short* __restrict__ Wt, int K, int N)
{
    int idx = blockIdx.x * 256 + threadIdx.x;
    if (idx >= K * N) return;
    int n = idx / K, k = idx % K;
    Wt[idx] = f2bf(W[(long)k * N + n]);
}

// ---- W2 scale+transpose with fused GRN snx: W2s[n][k] = bf16(W2[k][n]*snx[k]) ----
__global__ __launch_bounds__(256)
void wscale(const float* __restrict__ W2, const float* __restrict__ gx2,
            const float* __restrict__ gamma, unsigned short* __restrict__ W2s)
{
    __shared__ float red[256];
    int t = threadIdx.x;
    float s = 0.f;
#pragma unroll
    for (int i = 0; i < 3; ++i) s += sqrtf(gx2[t + i * 256]);
    red[t] = s; __syncthreads();
    for (int st = 128; st > 0; st >>= 1) {
        if (t < st) red[t] += red[t + st];
        __syncthreads();
    }
    float inv = 1.0f / (red[0] * (1.0f / C4) + 1e-6f);
    int idx = blockIdx.x * 256 + t;          // [n][k], k fastest
    int n = idx / C4, k = idx % C4;
    float snx = 1.0f + gamma[k] * sqrtf(gx2[k]) * inv;
    W2s[idx] = f2bf(W2[(long)k * Cn + n] * snx);
}

// ---- GEMM up (A-resident, 128-row panels — proven 129us in r15; the r17
// 64-row variant regressed: same VALU/MFMA busy-time, +23us stall from
// doubled B-load instructions). FETCH 23MB (A read once per panel).
__global__ __launch_bounds__(256)
void gemm_up(const unsigned short* __restrict__ A, const unsigned short* __restrict__ Bt,
             const float* __restrict__ bias, unsigned short* __restrict__ Y2,
             float* __restrict__ partial)
{
    __shared__ short Asm[128 * Cn];      // 49,152 B
    __shared__ float colsum[2][C4];      //  6,144 B
    int tid = threadIdx.x;
    int lane = tid & 63, wv = tid >> 6;
    int wm = wv >> 1, wn = wv & 1;
    int lr = lane & 15, lq = lane >> 4;
    long m0 = (long)blockIdx.x * 128;

    // stage A: 3072 bf16x8 chunks; chunk-XOR swizzle (cc ^= r&7, 24 chunks/row)
#pragma unroll
    for (int i = 0; i < 12; ++i) {
        int chunk = i * 256 + tid;
        int r = chunk / 24, cc = chunk - r * 24;
        bf16x8 v = *(const bf16x8*)(A + (size_t)(m0 + r) * Cn + cc * 8);
        *(bf16x8*)&Asm[r * Cn + ((cc ^ (r & 7)) * 8)] = v;
    }
    __syncthreads();

    for (int nt = 0; nt < 12; ++nt) {
        int n0 = nt * 64;
        f32x4 acc[4][2];
#pragma unroll
        for (int mi = 0; mi < 4; ++mi)
#pragma unroll
            for (int ni = 0; ni < 2; ++ni) acc[mi][ni] = (f32x4){0.f, 0.f, 0.f, 0.f};

#pragma unroll
        for (int ks = 0; ks < 6; ++ks) {
            bf16x8 af[4], bfr[2];
#pragma unroll
            for (int ni = 0; ni < 2; ++ni) {
                int nrow = n0 + wn * 32 + ni * 16 + lr;
                bfr[ni] = *(const bf16x8*)(Bt + (size_t)nrow * Cn + (ks * 4 + lq) * 8);
            }
#pragma unroll
            for (int mi = 0; mi < 4; ++mi) {
                int r = wm * 64 + mi * 16 + lr;
                int cc = (ks * 4 + lq) ^ (r & 7);
                af[mi] = *(const bf16x8*)&Asm[r * Cn + cc * 8];
            }
#pragma unroll
            for (int mi = 0; mi < 4; ++mi)
#pragma unroll
                for (int ni = 0; ni < 2; ++ni)
                    acc[mi][ni] = __builtin_amdgcn_mfma_f32_16x16x32_bf16(
                        af[mi], bfr[ni], acc[mi][ni], 0, 0, 0);
        }

        float ss[2] = {0.f, 0.f};
#pragma unroll
        for (int mi = 0; mi < 4; ++mi) {
#pragma unroll
            for (int ni = 0; ni < 2; ++ni) {
                int col = wn * 32 + ni * 16 + lr;
                float bb = bias[n0 + col];
                long row0 = m0 + wm * 64 + mi * 16 + lq * 4;
#pragma unroll
                for (int i = 0; i < 4; ++i) {
                    float v = gelu_tanh(acc[mi][ni][i] + bb);
                    ss[ni] = fmaf(v, v, ss[ni]);
                    Y2[(row0 + i) * C4 + n0 + col] = f2bf(v);
                }
            }
        }
#pragma unroll
        for (int ni = 0; ni < 2; ++ni) {
            ss[ni] += __shfl_xor(ss[ni], 16);
            ss[ni] += __shfl_xor(ss[ni], 32);
        }
        if (lq == 0) {
            colsum[wm][n0 + wn * 32 + lr]      = ss[0];
            colsum[wm][n0 + wn * 32 + 16 + lr] = ss[1];
        }
    }
    __syncthreads();
    for (int i = tid; i < C4; i += 256)
        partial[(size_t)blockIdx.x * C4 + i] = colsum[0][i] + colsum[1][i];
}

// ---- GEMM down (A-resident, r18): old grid (3n x 864m) fetched each y2
// m-panel 3x across XCD L2s (same overfetch bug r15 fixed in gemm_up).
// Now: one block per 128-row m-panel; loop 12 k-tiles staging A(128x64,16KB)
// once each; inner-loop all 3 n-tiles with B from L2-resident w2s (295KB).
// acc[3][4][2] fully unrolled (static indices -> registers).
__global__ __launch_bounds__(256)
void gemm_down(const unsigned short* __restrict__ A, const unsigned short* __restrict__ Bt,
               const float* __restrict__ beff, const float* __restrict__ x,
               float* __restrict__ out)
{
    __shared__ short Asm[128 * 64];      // 16,384 B
    int tid = threadIdx.x;
    int lane = tid & 63, wv = tid >> 6;
    int wm = wv >> 1, wn = wv & 1;
    int lr = lane & 15, lq = lane >> 4;
    long m0 = (long)blockIdx.x * 128;

    f32x4 acc[3][4][2];
#pragma unroll
    for (int nt = 0; nt < 3; ++nt)
#pragma unroll
        for (int mi = 0; mi < 4; ++mi)
#pragma unroll
            for (int ni = 0; ni < 2; ++ni) acc[nt][mi][ni] = (f32x4){0.f, 0.f, 0.f, 0.f};

    for (int k0 = 0; k0 < C4; k0 += 64) {
#pragma unroll
        for (int i = 0; i < 4; ++i) {
            int chunk = i * 256 + tid;
            int r = chunk >> 3, cc = chunk & 7;
            bf16x8 v = *(const bf16x8*)(A + (size_t)(m0 + r) * C4 + k0 + cc * 8);
            *(bf16x8*)&Asm[r * 64 + ((cc ^ (r & 7)) * 8)] = v;
        }
        __syncthreads();
#pragma unroll
        for (int ks = 0; ks < 2; ++ks) {
            bf16x8 af[4];
#pragma unroll
            for (int mi = 0; mi < 4; ++mi) {
                int r = wm * 64 + mi * 16 + lr;
                int cc = (ks * 4 + lq) ^ (r & 7);
                af[mi] = *(const bf16x8*)&Asm[r * 64 + cc * 8];
            }
#pragma unroll
            for (int nt = 0; nt < 3; ++nt) {
                bf16x8 bfr[2];
#pragma unroll
                for (int ni = 0; ni < 2; ++ni) {
                    int nrow = nt * 64 + wn * 32 + ni * 16 + lr;
                    bfr[ni] = *(const bf16x8*)(Bt + (size_t)nrow * C4 + k0 + (ks * 4 + lq) * 8);
                }
#pragma unroll
                for (int mi = 0; mi < 4; ++mi)
#pragma unroll
                    for (int ni = 0; ni < 2; ++ni)
                        acc[nt][mi][ni] = __builtin_amdgcn_mfma_f32_16x16x32_bf16(
                            af[mi], bfr[ni], acc[nt][mi][ni], 0, 0, 0);
            }
        }
        __syncthreads();
    }

#pragma unroll
    for (int nt = 0; nt < 3; ++nt) {
#pragma unroll
        for (int mi = 0; mi < 4; ++mi) {
#pragma unroll
            for (int ni = 0; ni < 2; ++ni) {
                int colg = nt * 64 + wn * 32 + ni * 16 + lr;
                float be = beff[colg];
                long mbase = m0 + wm * 64 + mi * 16 + lq * 4;
                const float* xp = x + (long)colg * DHW + mbase;
                float* op = out + (long)colg * DHW + mbase;
                float4 xvv = *(const float4*)xp;
                float4 o;
                o.x = acc[nt][mi][ni][0] + be + xvv.x;
                o.y = acc[nt][mi][ni][1] + be + xvv.y;
                o.z = acc[nt][mi][ni][2] + be + xvv.z;
                o.w = acc[nt][mi][ni][3] + be + xvv.w;
                *(float4*)op = o;
            }
        }
    }
}

// ---------------- GRN reduce: 864 partials -> gx2[n] ----------------
__global__ __launch_bounds__(256)
void grn_reduce(const float* __restrict__ partial, float* __restrict__ gx2)
{
    int n = blockIdx.x;
    const float* p = partial + n;
    float s = 0.f;
    for (int r = threadIdx.x; r < 864; r += 256) s += p[(long)r * C4];
    __shared__ float red[256];
    red[threadIdx.x] = s; __syncthreads();
    for (int st = 128; st > 0; st >>= 1) {
        if (threadIdx.x < st) red[threadIdx.x] += red[threadIdx.x + st];
        __syncthreads();
    }
    if (threadIdx.x == 0) gx2[n] = red[0];
}

// ---------------- effective down-bias: beff[j] = b2[j] + sum_k beta[k] W2[k][j] ----
__global__ __launch_bounds__(256)
void bias_eff_k(const float* __restrict__ beta, const float* __restrict__ W2,
                const float* __restrict__ b2, float* __restrict__ beff)
{
    __shared__ float red[256];
    int j = blockIdx.x, t = threadIdx.x;
    float s = 0.f;
#pragma unroll
    for (int i = 0; i < 3; ++i) {
        int k = t + i * 256;
        s = fmaf(beta[k], W2[(long)k * Cn + j], s);
    }
    red[t] = s; __syncthreads();
    for (int st = 128; st > 0; st >>= 1) {
        if (t < st) red[t] += red[t + st];
        __syncthreads();
    }
    if (t == 0) beff[j] = red[0] + b2[j];
}

extern "C" void kernel_launch(void* const* d_in, const int* in_sizes, int n_in,
                              void* d_out, int out_size, void* d_ws, size_t ws_size,
                              hipStream_t stream) {
    const float* x      = (const float*)d_in[0];
    const float* conv_w = (const float*)d_in[1];
    const float* conv_b = (const float*)d_in[2];
    const float* ln_g   = (const float*)d_in[3];
    const float* ln_b   = (const float*)d_in[4];
    const float* w1     = (const float*)d_in[5];
    const float* b1     = (const float*)d_in[6];
    const float* gg     = (const float*)d_in[7];
    const float* gb     = (const float*)d_in[8];
    const float* w2     = (const float*)d_in[9];
    const float* b2     = (const float*)d_in[10];
    float* out = (float*)d_out;
    char* ws = (char*)d_ws;

    // liveness-proven layout (~215.6 MB):
    //   [0, 42.5M)       yc   (conv out; dead after ln)
    //   [42.5M, 99.1M)   xbf  (padded x; dead after conv)
    //   [0, 169.9M)      y2   (gemm_up out; overlaps yc+xbf, both dead)
    //   [169.9M, 212.3M) y1   (ln out; live through gemm_up)
    //   [202.7M, 212.3M) btp  (inside y1 range — dead before ln writes; ok)
    //   [212.3M, 215.0M) partial f32 [864][768]  (AFTER y1 — safe)
    //   [215.0M, ...]    w1t, w2s, gx2, beff
    unsigned short* yc  = (unsigned short*)(ws);
    unsigned short* xbf = (unsigned short*)(ws + 42467328L);
    unsigned short* y2  = (unsigned short*)(ws);
    unsigned short* y1  = (unsigned short*)(ws + 169869312L);
    unsigned short* btp = (unsigned short*)(ws + 202702848L);
    float*     partial  = (float*)(ws + 212336640L);
    unsigned short* w1t = (unsigned short*)(ws + 214990848L);
    unsigned short* w2s = (unsigned short*)(ws + 215285760L);
    float*         gx2  = (float*)(ws + 215580672L);
    float*        beff  = (float*)(ws + 215586816L);

    bias_eff_k<<<Cn, 256, 0, stream>>>(gb, w2, b2, beff);
    wtrans<<<(Cn * C4 + 255) / 256, 256, 0, stream>>>(w1, w1t, Cn, C4);

    for (int b = 0; b < Bn; ++b) {
        const float* xb = x + (size_t)b * CDHW;
        float* outb = out + (size_t)b * CDHW;
        xpad_k<<<(Cn * 2304 * 8) / 256, 256, 0, stream>>>(xb, xbf);
        btoep_k<<<(Cn * 49 * 64) / 256, 256, 0, stream>>>(conv_w, btp);
        dim3 gc(27, Cn);                  // 3x3x3 tiles of 16^3
        conv_dw<<<gc, 128, 0, stream>>>(xbf, btp, conv_b, yc);
        ln_kernel<<<Dn * Hn, 256, 0, stream>>>(yc, ln_g, ln_b, y1);
        gemm_up<<<DHW / 128, 256, 0, stream>>>(y1, w1t, b1, y2, partial);
        grn_reduce<<<C4, 256, 0, stream>>>(partial, gx2);
        wscale<<<(Cn * C4) / 256, 256, 0, stream>>>(w2, gx2, gg, w2s);
        gemm_down<<<DHW / 128, 256, 0, stream>>>(y2, w2s, beff, xb, outb);
    }
}

// Round 20
// 779.849 us; speedup vs baseline: 1.1010x; 1.1010x over previous
//
#include <hip/hip_runtime.h>
#include <math.h>

#define Bn 2
#define Cn 192
#define Dn 48
#define Hn 48
#define Wn 48
#define C4 768
#define DHW (Dn*Hn*Wn)          // 110592 per batch
#define CDHW ((long)Cn*DHW)     // 21233664 per batch

typedef __attribute__((ext_vector_type(8))) short bf16x8;
typedef __attribute__((ext_vector_type(4))) float f32x4;

__device__ inline float bf2f(unsigned short u) {
    union { float f; unsigned int i; } v; v.i = ((unsigned int)u) << 16; return v.f;
}
__device__ inline unsigned short f2bf(float f) {
    union { float f; unsigned int i; } v; v.f = f;
    unsigned int r = v.i + 0x7FFFu + ((v.i >> 16) & 1u);   // RNE
    return (unsigned short)(r >> 16);
}
__device__ inline float blo(unsigned int u) {
    union { unsigned int i; float f; } v; v.i = u << 16; return v.f;
}
__device__ inline float bhi(unsigned int u) {
    union { unsigned int i; float f; } v; v.i = u & 0xffff0000u; return v.f;
}
__device__ inline unsigned int cvtpk_bf16(float lo, float hi) {
    unsigned int r;
    asm("v_cvt_pk_bf16_f32 %0, %1, %2" : "=v"(r) : "v"(lo), "v"(hi));
    return r;
}
// tanh-form GELU, rcp-based (r19: full-precision divide was ~10 VALU ops;
// v_rcp_f32 + mul is 2, rel err ~1e-7 — negligible vs bf16 storage).
__device__ inline float gelu_tanh(float v) {
    float u = v * fmaf(0.0356774081f, v * v, 0.7978845608f);
    float a = fabsf(u);
    float t = __expf(-2.0f * a);
    float th = (1.0f - t) * __builtin_amdgcn_rcpf(1.0f + t);
    th = copysignf(th, u);
    return 0.5f * v * (1.0f + th);
}

// ---- x pre-pad: NCDHW f32 -> xbf[c][d][h][64] bf16, w zero-padded +-8 ----
__global__ __launch_bounds__(256)
void xpad_k(const float* __restrict__ x, unsigned short* __restrict__ xbf)
{
    int u = blockIdx.x * 256 + threadIdx.x;     // row*8 + j
    int j = u & 7;
    int row = u >> 3;                            // c*2304 + d*48 + h
    unsigned short* orow = xbf + ((size_t)row << 6);
    uint4 o = {0u, 0u, 0u, 0u};
    if (j >= 1 && j <= 6) {
        const float* xr = x + (size_t)row * 48 + (8 * j - 8);
        float4 a = *(const float4*)xr;
        float4 b = *(const float4*)(xr + 4);
        o.x = cvtpk_bf16(a.x, a.y); o.y = cvtpk_bf16(a.z, a.w);
        o.z = cvtpk_bf16(b.x, b.y); o.w = cvtpk_bf16(b.z, b.w);
    }
    *(uint4*)(orow + 8 * j) = o;
}

// ---- B-Toeplitz table: btp[(c*49+kdkh)*64+lane][j] = wt[kdkh][8g+j-n-5] ----
__global__ __launch_bounds__(256)
void btoep_k(const float* __restrict__ cw, unsigned short* __restrict__ btp)
{
    int idx = blockIdx.x * 256 + threadIdx.x;   // (c*49 + kdkh)*64 + lane
    int lane = idx & 63;
    int t = idx >> 6;
    int kdkh = t % 49, c = t / 49;
    int n = lane & 15, g = lane >> 4;
    unsigned short v[8];
#pragma unroll
    for (int j = 0; j < 8; ++j) {
        int kw = 8 * g + j - n - 5;
        v[j] = (kw >= 0 && kw <= 6) ? f2bf(cw[(kdkh * 7 + kw) * Cn + c])
                                    : (unsigned short)0;
    }
    *(uint4*)(btp + (size_t)idx * 8) = *(uint4*)v;
}

// ---------------- depthwise conv 7x7x7 on the MATRIX pipe (Toeplitz MFMA) ----
#define CTD 16
#define CHD (CTD+6)   // 22
#define CHH 22

__global__ __launch_bounds__(128)
void conv_dw(const unsigned short* __restrict__ xbf, const unsigned short* __restrict__ btp,
             const float* __restrict__ cb, unsigned short* __restrict__ yc)
{
    __shared__ unsigned int xt[CHD * CHH * 16];   // 30,976 B
    int c = blockIdx.y;
    int s = blockIdx.x;                           // 27 tiles: 3x3x3 of 16^3
    int wt = s % 3, ht = (s / 3) % 3, dt = s / 9;
    int d0 = dt * 16, h0 = ht * 16, w0 = wt * 16;
    int tid = threadIdx.x;

    const unsigned short* xc = xbf + ((size_t)c * 2304 << 6);
    for (int u = tid; u < CHD * CHH * 4; u += 128) {
        int g = u & 3, r2 = u >> 2;
        int hh2 = r2 % CHH, dd = r2 / CHH;
        int gd = d0 - 3 + dd, gh = h0 - 3 + hh2;
        uint4 v = {0u, 0u, 0u, 0u};
        if ((unsigned)gd < 48u && (unsigned)gh < 48u)
            v = *(const uint4*)(xc + (((size_t)gd * 48 + gh) << 6) + w0 + 8 * g);
        *(uint4*)&xt[(r2 << 4) + ((g ^ (r2 & 3)) << 2)] = v;
    }
    __syncthreads();

    int lane = tid & 63, wv = tid >> 6;
    int lr = lane & 15, g = lane >> 4;
    float bias = cb[c];
    f32x4 acc[8];
#pragma unroll
    for (int t = 0; t < 8; ++t) acc[t] = (f32x4){bias, bias, bias, bias};

    const unsigned short* bchan = btp + (size_t)c * 49 * 512;
    const unsigned short* xt16 = (const unsigned short*)xt;

    for (int kh = 0; kh < 7; ++kh) {
        bf16x8 Bf[7];
#pragma unroll
        for (int kd = 0; kd < 7; ++kd)
            Bf[kd] = *(const bf16x8*)(bchan + (size_t)((kd * 7 + kh) * 64 + lane) * 8);
#pragma unroll
        for (int p = 0; p < 14; ++p) {
            int r2 = (8 * wv + p) * CHH + kh + lr;
            bf16x8 Af = *(const bf16x8*)(xt16 + (r2 << 5) + ((g ^ (r2 & 3)) << 3));
#pragma unroll
            for (int kd = 0; kd < 7; ++kd) {
                int t = p - kd;
                if (t < 0 || t > 7) continue;     // folds at compile time
                acc[t] = __builtin_amdgcn_mfma_f32_16x16x32_bf16(Af, Bf[kd], acc[t], 0, 0, 0);
            }
        }
    }

    unsigned short* yb = yc + (long)c * DHW;
#pragma unroll
    for (int t = 0; t < 8; ++t) {
        int d = d0 + 8 * wv + t;
#pragma unroll
        for (int i = 0; i < 4; ++i) {
            int h = h0 + g * 4 + i;
            yb[((long)d * 48 + h) * 48 + w0 + lr] = f2bf(acc[t][i]);
        }
    }
}

// ---------------- LayerNorm over C, per-batch NCDHW(bf16) -> NDHWC (bf16) ----------------
__global__ __launch_bounds__(256)
void ln_kernel(const unsigned short* __restrict__ yc, const float* __restrict__ g,
               const float* __restrict__ lb, unsigned short* __restrict__ y1)
{
    __shared__ float tile[Cn * Wn];
    __shared__ float qs1[4][48], qs2[4][48];
    __shared__ float mu_s[Wn], rs_s[Wn];
    int dh = blockIdx.x;
    long rowbase = (long)dh * Wn;
    for (int l = threadIdx.x; l < Cn * 24; l += 256) {
        int c = l / 24, wp = l % 24;
        unsigned int u = *(const unsigned int*)&yc[rowbase + (long)c * DHW + wp * 2];
        tile[c * Wn + wp * 2]     = blo(u);
        tile[c * Wn + wp * 2 + 1] = bhi(u);
    }
    __syncthreads();
    if (threadIdx.x < 192) {
        int w = threadIdx.x >> 2, q = threadIdx.x & 3;
        float s1 = 0.f, s2 = 0.f;
        for (int cc = 0; cc < 48; ++cc) {
            float v = tile[(cc * 4 + q) * Wn + w];
            s1 += v; s2 = fmaf(v, v, s2);
        }
        qs1[q][w] = s1; qs2[q][w] = s2;
    }
    __syncthreads();
    if (threadIdx.x < 48) {
        int w = threadIdx.x;
        float s1 = qs1[0][w] + qs1[1][w] + qs1[2][w] + qs1[3][w];
        float s2 = qs2[0][w] + qs2[1][w] + qs2[2][w] + qs2[3][w];
        float mu = s1 * (1.0f / Cn);
        float var = s2 * (1.0f / Cn) - mu * mu;
        mu_s[w] = mu;
        rs_s[w] = rsqrtf(var + 1e-6f);
    }
    __syncthreads();
    long obase = (long)dh * Wn * Cn;
    for (int l = threadIdx.x; l < Cn * Wn; l += 256) {
        int w = l / Cn, c = l % Cn;
        float val = (tile[c * Wn + w] - mu_s[w]) * rs_s[w] * g[c] + lb[c];
        y1[obase + l] = f2bf(val);
    }
}

// ---------------- weight transpose+bf16: Wt[n][k] = bf16(W[k][n]) ----------------
__global__ __launch_bounds__(256)
void wtrans(const float* __restrict__ W, unsigned short* __restrict__ Wt, int K, int N)
{
    int idx = blockIdx.x * 256 + threadIdx.x;
    if (idx >= K * N) return;
    int n = idx / K, k = idx % K;
    Wt[idx] = f2bf(W[(long)k * N + n]);
}

// ---- W2 scale+transpose with fused GRN snx: W2s[n][k] = bf16(W2[k][n]*snx[k]) ----
__global__ __launch_bounds__(256)
void wscale(const float* __restrict__ W2, const float* __restrict__ gx2,
            const float* __restrict__ gamma, unsigned short* __restrict__ W2s)
{
    __shared__ float red[256];
    int t = threadIdx.x;
    float s = 0.f;
#pragma unroll
    for (int i = 0; i < 3; ++i) s += sqrtf(gx2[t + i * 256]);
    red[t] = s; __syncthreads();
    for (int st = 128; st > 0; st >>= 1) {
        if (t < st) red[t] += red[t + st];
        __syncthreads();
    }
    float inv = 1.0f / (red[0] * (1.0f / C4) + 1e-6f);
    int idx = blockIdx.x * 256 + t;          // [n][k], k fastest
    int n = idx / C4, k = idx % C4;
    float snx = 1.0f + gamma[k] * sqrtf(gx2[k]) * inv;
    W2s[idx] = f2bf(W2[(long)k * Cn + n] * snx);
}

// ---- GEMM up (A-resident, 128-row panels — proven 129us/23MB-FETCH in r15;
// 64-row variant regressed r18: +23us stall from doubled B-load instructions).
__global__ __launch_bounds__(256)
void gemm_up(const unsigned short* __restrict__ A, const unsigned short* __restrict__ Bt,
             const float* __restrict__ bias, unsigned short* __restrict__ Y2,
             float* __restrict__ partial)
{
    __shared__ short Asm[128 * Cn];      // 49,152 B
    __shared__ float colsum[2][C4];      //  6,144 B
    int tid = threadIdx.x;
    int lane = tid & 63, wv = tid >> 6;
    int wm = wv >> 1, wn = wv & 1;
    int lr = lane & 15, lq = lane >> 4;
    long m0 = (long)blockIdx.x * 128;

    // stage A: 3072 bf16x8 chunks; chunk-XOR swizzle (cc ^= r&7, 24 chunks/row)
#pragma unroll
    for (int i = 0; i < 12; ++i) {
        int chunk = i * 256 + tid;
        int r = chunk / 24, cc = chunk - r * 24;
        bf16x8 v = *(const bf16x8*)(A + (size_t)(m0 + r) * Cn + cc * 8);
        *(bf16x8*)&Asm[r * Cn + ((cc ^ (r & 7)) * 8)] = v;
    }
    __syncthreads();

    for (int nt = 0; nt < 12; ++nt) {
        int n0 = nt * 64;
        f32x4 acc[4][2];
#pragma unroll
        for (int mi = 0; mi < 4; ++mi)
#pragma unroll
            for (int ni = 0; ni < 2; ++ni) acc[mi][ni] = (f32x4){0.f, 0.f, 0.f, 0.f};

#pragma unroll
        for (int ks = 0; ks < 6; ++ks) {
            bf16x8 af[4], bfr[2];
#pragma unroll
            for (int ni = 0; ni < 2; ++ni) {
                int nrow = n0 + wn * 32 + ni * 16 + lr;
                bfr[ni] = *(const bf16x8*)(Bt + (size_t)nrow * Cn + (ks * 4 + lq) * 8);
            }
#pragma unroll
            for (int mi = 0; mi < 4; ++mi) {
                int r = wm * 64 + mi * 16 + lr;
                int cc = (ks * 4 + lq) ^ (r & 7);
                af[mi] = *(const bf16x8*)&Asm[r * Cn + cc * 8];
            }
#pragma unroll
            for (int mi = 0; mi < 4; ++mi)
#pragma unroll
                for (int ni = 0; ni < 2; ++ni)
                    acc[mi][ni] = __builtin_amdgcn_mfma_f32_16x16x32_bf16(
                        af[mi], bfr[ni], acc[mi][ni], 0, 0, 0);
        }

        float ss[2] = {0.f, 0.f};
#pragma unroll
        for (int mi = 0; mi < 4; ++mi) {
#pragma unroll
            for (int ni = 0; ni < 2; ++ni) {
                int col = wn * 32 + ni * 16 + lr;
                float bb = bias[n0 + col];
                long row0 = m0 + wm * 64 + mi * 16 + lq * 4;
#pragma unroll
                for (int i = 0; i < 4; ++i) {
                    float v = gelu_tanh(acc[mi][ni][i] + bb);
                    ss[ni] = fmaf(v, v, ss[ni]);
                    Y2[(row0 + i) * C4 + n0 + col] = f2bf(v);
                }
            }
        }
#pragma unroll
        for (int ni = 0; ni < 2; ++ni) {
            ss[ni] += __shfl_xor(ss[ni], 16);
            ss[ni] += __shfl_xor(ss[ni], 32);
        }
        if (lq == 0) {
            colsum[wm][n0 + wn * 32 + lr]      = ss[0];
            colsum[wm][n0 + wn * 32 + 16 + lr] = ss[1];
        }
    }
    __syncthreads();
    for (int i = tid; i < C4; i += 256)
        partial[(size_t)blockIdx.x * C4 + i] = colsum[0][i] + colsum[1][i];
}

// ================= MFMA GEMM down: r19 revert to proven 2-barrier tiled form.
// (r18's A-resident variant was latency-bound: 864 blocks, all pipes <10%.
//  The 3x y2 "overfetch" is L3-absorbed — y2 170MB < 256MB L3 — so the old
//  grid (3n x 864m, 2592 blocks) is the faster structure at ~115us.)
#define BM 128
#define BN 64
#define BK 64

__global__ __launch_bounds__(256)
void gemm_down(const unsigned short* __restrict__ A, const unsigned short* __restrict__ Bt,
               const float* __restrict__ beff, const float* __restrict__ x,
               float* __restrict__ out)
{
    __shared__ short Asm[BM * BK];
    __shared__ short Bsm[BN * BK];
    int tid = threadIdx.x;
    int lane = tid & 63, wv = tid >> 6;
    int wm = wv >> 1, wn = wv & 1;
    int lr = lane & 15, lq = lane >> 4;
    long m0 = (long)blockIdx.y * BM;
    int n0 = blockIdx.x * BN;

    f32x4 acc[4][2];
#pragma unroll
    for (int mi = 0; mi < 4; ++mi)
#pragma unroll
        for (int ni = 0; ni < 2; ++ni) acc[mi][ni] = (f32x4){0.f, 0.f, 0.f, 0.f};

    for (int k0 = 0; k0 < C4; k0 += BK) {
#pragma unroll
        for (int i = 0; i < 4; ++i) {
            int chunk = i * 256 + tid;
            int r = chunk >> 3, cc = chunk & 7;
            bf16x8 v = *(const bf16x8*)(A + (size_t)(m0 + r) * C4 + k0 + cc * 8);
            *(bf16x8*)&Asm[r * BK + ((cc ^ (r & 7)) * 8)] = v;
        }
#pragma unroll
        for (int i = 0; i < 2; ++i) {
            int chunk = i * 256 + tid;
            int r = chunk >> 3, cc = chunk & 7;
            bf16x8 v = *(const bf16x8*)(Bt + (size_t)(n0 + r) * C4 + k0 + cc * 8);
            *(bf16x8*)&Bsm[r * BK + ((cc ^ (r & 7)) * 8)] = v;
        }
        __syncthreads();
#pragma unroll
        for (int kk = 0; kk < 2; ++kk) {
            bf16x8 af[4], bfr[2];
#pragma unroll
            for (int mi = 0; mi < 4; ++mi) {
                int r = wm * 64 + mi * 16 + lr;
                int cc = (kk * 4 + lq) ^ (r & 7);
                af[mi] = *(const bf16x8*)&Asm[r * BK + cc * 8];
            }
#pragma unroll
            for (int ni = 0; ni < 2; ++ni) {
                int r = wn * 32 + ni * 16 + lr;
                int cc = (kk * 4 + lq) ^ (r & 7);
                bfr[ni] = *(const bf16x8*)&Bsm[r * BK + cc * 8];
            }
#pragma unroll
            for (int mi = 0; mi < 4; ++mi)
#pragma unroll
                for (int ni = 0; ni < 2; ++ni)
                    acc[mi][ni] = __builtin_amdgcn_mfma_f32_16x16x32_bf16(
                        af[mi], bfr[ni], acc[mi][ni], 0, 0, 0);
        }
        __syncthreads();
    }

#pragma unroll
    for (int mi = 0; mi < 4; ++mi) {
#pragma unroll
        for (int ni = 0; ni < 2; ++ni) {
            int colg = n0 + wn * 32 + ni * 16 + lr;
            float be = beff[colg];
            long mbase = m0 + wm * 64 + mi * 16 + lq * 4;
            const float* xp = x + (long)colg * DHW + mbase;
            float* op = out + (long)colg * DHW + mbase;
            float4 xvv = *(const float4*)xp;
            float4 o;
            o.x = acc[mi][ni][0] + be + xvv.x;
            o.y = acc[mi][ni][1] + be + xvv.y;
            o.z = acc[mi][ni][2] + be + xvv.z;
            o.w = acc[mi][ni][3] + be + xvv.w;
            *(float4*)op = o;
        }
    }
}

// ---------------- GRN reduce: 864 partials -> gx2[n] ----------------
__global__ __launch_bounds__(256)
void grn_reduce(const float* __restrict__ partial, float* __restrict__ gx2)
{
    int n = blockIdx.x;
    const float* p = partial + n;
    float s = 0.f;
    for (int r = threadIdx.x; r < 864; r += 256) s += p[(long)r * C4];
    __shared__ float red[256];
    red[threadIdx.x] = s; __syncthreads();
    for (int st = 128; st > 0; st >>= 1) {
        if (threadIdx.x < st) red[threadIdx.x] += red[threadIdx.x + st];
        __syncthreads();
    }
    if (threadIdx.x == 0) gx2[n] = red[0];
}

// ---------------- effective down-bias: beff[j] = b2[j] + sum_k beta[k] W2[k][j] ----
__global__ __launch_bounds__(256)
void bias_eff_k(const float* __restrict__ beta, const float* __restrict__ W2,
                const float* __restrict__ b2, float* __restrict__ beff)
{
    __shared__ float red[256];
    int j = blockIdx.x, t = threadIdx.x;
    float s = 0.f;
#pragma unroll
    for (int i = 0; i < 3; ++i) {
        int k = t + i * 256;
        s = fmaf(beta[k], W2[(long)k * Cn + j], s);
    }
    red[t] = s; __syncthreads();
    for (int st = 128; st > 0; st >>= 1) {
        if (t < st) red[t] += red[t + st];
        __syncthreads();
    }
    if (t == 0) beff[j] = red[0] + b2[j];
}

extern "C" void kernel_launch(void* const* d_in, const int* in_sizes, int n_in,
                              void* d_out, int out_size, void* d_ws, size_t ws_size,
                              hipStream_t stream) {
    const float* x      = (const float*)d_in[0];
    const float* conv_w = (const float*)d_in[1];
    const float* conv_b = (const float*)d_in[2];
    const float* ln_g   = (const float*)d_in[3];
    const float* ln_b   = (const float*)d_in[4];
    const float* w1     = (const float*)d_in[5];
    const float* b1     = (const float*)d_in[6];
    const float* gg     = (const float*)d_in[7];
    const float* gb     = (const float*)d_in[8];
    const float* w2     = (const float*)d_in[9];
    const float* b2     = (const float*)d_in[10];
    float* out = (float*)d_out;
    char* ws = (char*)d_ws;

    // liveness-proven layout (~215.6 MB):
    //   [0, 42.5M)       yc   (conv out; dead after ln)
    //   [42.5M, 99.1M)   xbf  (padded x; dead after conv)
    //   [0, 169.9M)      y2   (gemm_up out; overlaps yc+xbf, both dead)
    //   [169.9M, 212.3M) y1   (ln out; live through gemm_up)
    //   [202.7M, 212.3M) btp  (inside y1 range — dead before ln writes; ok)
    //   [212.3M, 215.0M) partial f32 [864][768]  (AFTER y1 — safe)
    //   [215.0M, ...]    w1t, w2s, gx2, beff
    unsigned short* yc  = (unsigned short*)(ws);
    unsigned short* xbf = (unsigned short*)(ws + 42467328L);
    unsigned short* y2  = (unsigned short*)(ws);
    unsigned short* y1  = (unsigned short*)(ws + 169869312L);
    unsigned short* btp = (unsigned short*)(ws + 202702848L);
    float*     partial  = (float*)(ws + 212336640L);
    unsigned short* w1t = (unsigned short*)(ws + 214990848L);
    unsigned short* w2s = (unsigned short*)(ws + 215285760L);
    float*         gx2  = (float*)(ws + 215580672L);
    float*        beff  = (float*)(ws + 215586816L);

    bias_eff_k<<<Cn, 256, 0, stream>>>(gb, w2, b2, beff);
    wtrans<<<(Cn * C4 + 255) / 256, 256, 0, stream>>>(w1, w1t, Cn, C4);

    for (int b = 0; b < Bn; ++b) {
        const float* xb = x + (size_t)b * CDHW;
        float* outb = out + (size_t)b * CDHW;
        xpad_k<<<(Cn * 2304 * 8) / 256, 256, 0, stream>>>(xb, xbf);
        btoep_k<<<(Cn * 49 * 64) / 256, 256, 0, stream>>>(conv_w, btp);
        dim3 gc(27, Cn);                  // 3x3x3 tiles of 16^3
        conv_dw<<<gc, 128, 0, stream>>>(xbf, btp, conv_b, yc);
        ln_kernel<<<Dn * Hn, 256, 0, stream>>>(yc, ln_g, ln_b, y1);
        gemm_up<<<DHW / 128, 256, 0, stream>>>(y1, w1t, b1, y2, partial);
        grn_reduce<<<C4, 256, 0, stream>>>(partial, gx2);
        wscale<<<(Cn * C4) / 256, 256, 0, stream>>>(w2, gx2, gg, w2s);
        dim3 gd(Cn / BN, DHW / BM);       // (3, 864) — proven faster (L3 absorbs A re-reads)
        gemm_down<<<gd, 256, 0, stream>>>(y2, w2s, beff, xb, outb);
    }
}